// Round 9
// baseline (351.368 us; speedup 1.0000x reference)
//
#include <hip/hip_runtime.h>
#include <math.h>

typedef __attribute__((ext_vector_type(8))) short short8;
typedef __attribute__((ext_vector_type(4))) float float4v;

#define EPB 2048       // edges per block for bin (8/thread)
#define EPT 8
#define CAP 2048       // slab capacity per bucket (mean ~1024, +32 sigma)
#define CAPSH 11

__device__ __forceinline__ unsigned short f2bf(float f) {
  unsigned int u = __float_as_uint(f);
  unsigned int r = (u + 0x7fffu + ((u >> 16) & 1u)) >> 16;  // RNE
  return (unsigned short)r;
}
__device__ __forceinline__ float bf2f(unsigned u16) {
  return __uint_as_float(u16 << 16);
}

struct SetFull {
  const int* src; const int* dst; const float* w;
  int* offs;   // row offsets, per-bucket layout: idx = row + (row>>shift)
  int* pkd;    // packed per-(block,bucket) run table: (off<<16)|cnt
  int E, N, shift, nb, cntBase, blkBase, B;
};
struct All4 { SetFull s[4]; };

// ---------------------------------------------------------------------------
// Weight conversion: W[K][128] fp32 -> frag-major bf16.
// ---------------------------------------------------------------------------
__global__ __launch_bounds__(256) void conv_w_kernel(
    const float* __restrict__ W1a, const float* __restrict__ W1b,
    const float* __restrict__ W2a, const float* __restrict__ W2b,
    unsigned short* __restrict__ F1a, unsigned short* __restrict__ F1b,
    unsigned short* __restrict__ F2a, unsigned short* __restrict__ F2b) {
  int t = blockIdx.x * 256 + threadIdx.x;
  const float* W; unsigned short* F; int KB;
  if (t < 4096) { W = W1a; F = F1a; KB = 8; }
  else if (t < 6144) { W = W1b; F = F1b; KB = 4; t -= 4096; }
  else if (t < 10240) { W = W2a; F = F2a; KB = 8; t -= 6144; }
  else if (t < 12288) { W = W2b; F = F2b; KB = 4; t -= 10240; }
  else return;
  int lane = t & 63;
  int frag = t >> 6;
  int nt = frag / KB;
  int kb = frag - nt * KB;
  int k = kb * 32 + (lane >> 4) * 8;
  int n = nt * 16 + (lane & 15);
  unsigned short v[8];
  #pragma unroll
  for (int j = 0; j < 8; ++j) v[j] = f2bf(W[(long long)(k + j) * 128 + n]);
  unsigned short* o = F + ((long long)frag * 64 + lane) * 8;
  *reinterpret_cast<int4*>(o) = *reinterpret_cast<int4*>(v);
}

// fp32 -> packed bf16 pairs (for word_emb)
__global__ __launch_bounds__(256) void conv_bf16_kernel(
    const float* __restrict__ in, unsigned* __restrict__ out, int npairs) {
  int t = blockIdx.x * 256 + threadIdx.x;
  if (t >= npairs) return;
  float2 v = reinterpret_cast<const float2*>(in)[t];
  out[t] = (unsigned)f2bf(v.x) | ((unsigned)f2bf(v.y) << 16);
}

// ---------------------------------------------------------------------------
// Layer-1 MFMA GEMM, fp32 A (K=256), N1+N2 FUSED: Y bf16 = relu(X@W+b).
// Weights LDS-STAGED once per block (64KB, all 4 waves share); B-fragment
// reads become conflict-free ds_read_b128 (~12cy) instead of L2 round-trips
// (~200cy) — the round-7/8 PMC showed the MFMA loop was B-load-latency-bound.
// A row preloaded+pinned before staging so its 16 loads fly underneath.
// ---------------------------------------------------------------------------
template <int K>
__global__ __launch_bounds__(256) void gemm1_kernel(
    const float* __restrict__ X1, const unsigned short* __restrict__ W1,
    const float* __restrict__ bias1, unsigned short* __restrict__ Y1, int N1,
    const float* __restrict__ X2, const unsigned short* __restrict__ W2,
    const float* __restrict__ bias2, unsigned short* __restrict__ Y2, int N2) {
  constexpr int KB = K / 32;
  constexpr int FRAGS = 8 * KB;            // frag count (64 lanes x 16B each)
  __shared__ int4 Flds[FRAGS * 64];        // 64KB for K=256
  const int lane = threadIdx.x & 63;
  const int wave = threadIdx.x >> 6;
  int nb1 = (N1 + 63) >> 6;
  int blk = blockIdx.x;
  const float* X; const unsigned short* Wf; const float* bias;
  unsigned short* Y; int N;
  if (blk < nb1) { X = X1; Wf = W1; bias = bias1; Y = Y1; N = N1; }
  else { blk -= nb1; X = X2; Wf = W2; bias = bias2; Y = Y2; N = N2; }
  const int m_base = blk * 64 + wave * 16;

  int arow = m_base + (lane & 15);
  if (arow >= N) arow = N - 1;
  const float* aptr = X + (long long)arow * K + (lane >> 4) * 8;

  // preload entire A row slice: all 2*KB loads issued back-to-back
  float4 a[2 * KB];
  #pragma unroll
  for (int i = 0; i < 2 * KB; ++i)
    a[i] = *reinterpret_cast<const float4*>(aptr + (i >> 1) * 32 + (i & 1) * 4);
  asm volatile("" ::: "memory");  // pin A loads above staging

  // cooperative weight staging: coalesced, fully independent int4 loads
  {
    const int4* src = (const int4*)Wf;
    for (int i = threadIdx.x; i < FRAGS * 64; i += 256) Flds[i] = src[i];
  }
  __syncthreads();

  float4v acc[8];
  #pragma unroll
  for (int nt = 0; nt < 8; ++nt) acc[nt] = (float4v)(0.f);

  #pragma unroll
  for (int kb = 0; kb < KB; ++kb) {
    float4 a0 = a[2 * kb];
    float4 a1 = a[2 * kb + 1];
    unsigned short u[8];
    u[0] = f2bf(a0.x); u[1] = f2bf(a0.y); u[2] = f2bf(a0.z); u[3] = f2bf(a0.w);
    u[4] = f2bf(a1.x); u[5] = f2bf(a1.y); u[6] = f2bf(a1.z); u[7] = f2bf(a1.w);
    short8 afrag = *reinterpret_cast<short8*>(u);
    #pragma unroll
    for (int nt = 0; nt < 8; ++nt) {
      int4 braw = Flds[(nt * KB + kb) * 64 + lane];
      short8 bfrag = *reinterpret_cast<short8*>(&braw);
      acc[nt] = __builtin_amdgcn_mfma_f32_16x16x32_bf16(afrag, bfrag, acc[nt], 0, 0, 0);
    }
  }

  const int col = lane & 15;
  const int rbase = (lane >> 4) * 4;
  #pragma unroll
  for (int nt = 0; nt < 8; ++nt) {
    int n = nt * 16 + col;
    float b = bias[n];
    #pragma unroll
    for (int r = 0; r < 4; ++r) {
      int grow = m_base + rbase + r;
      if (grow < N) Y[(long long)grow * 128 + n] = f2bf(fmaxf(acc[nt][r] + b, 0.f));
    }
  }
}

// ---------------------------------------------------------------------------
// Layer-2 MFMA GEMM, bf16 A (K=128), h11+h22 FUSED. Weights LDS-staged (32KB).
// ---------------------------------------------------------------------------
template <int K>
__global__ __launch_bounds__(256) void gemm2_kernel(
    const unsigned short* __restrict__ X1, const unsigned short* __restrict__ W1,
    const float* __restrict__ bias1, unsigned short* __restrict__ Y1, int N1,
    const unsigned short* __restrict__ X2, const unsigned short* __restrict__ W2,
    const float* __restrict__ bias2, unsigned short* __restrict__ Y2, int N2) {
  constexpr int KB = K / 32;
  constexpr int FRAGS = 8 * KB;
  __shared__ int4 Flds[FRAGS * 64];        // 32KB for K=128
  const int lane = threadIdx.x & 63;
  const int wave = threadIdx.x >> 6;
  int nb1 = (N1 + 63) >> 6;
  int blk = blockIdx.x;
  const unsigned short* X; const unsigned short* Wf; const float* bias;
  unsigned short* Y; int N;
  if (blk < nb1) { X = X1; Wf = W1; bias = bias1; Y = Y1; N = N1; }
  else { blk -= nb1; X = X2; Wf = W2; bias = bias2; Y = Y2; N = N2; }
  const int m_base = blk * 64 + wave * 16;

  int arow = m_base + (lane & 15);
  if (arow >= N) arow = N - 1;
  const unsigned short* aptr = X + (long long)arow * K + (lane >> 4) * 8;

  short8 a[KB];
  #pragma unroll
  for (int kb = 0; kb < KB; ++kb)
    a[kb] = *reinterpret_cast<const short8*>(aptr + kb * 32);
  asm volatile("" ::: "memory");  // pin A loads above staging

  {
    const int4* src = (const int4*)Wf;
    for (int i = threadIdx.x; i < FRAGS * 64; i += 256) Flds[i] = src[i];
  }
  __syncthreads();

  float4v acc[8];
  #pragma unroll
  for (int nt = 0; nt < 8; ++nt) acc[nt] = (float4v)(0.f);

  #pragma unroll
  for (int kb = 0; kb < KB; ++kb) {
    #pragma unroll
    for (int nt = 0; nt < 8; ++nt) {
      int4 braw = Flds[(nt * KB + kb) * 64 + lane];
      short8 bfrag = *reinterpret_cast<short8*>(&braw);
      acc[nt] = __builtin_amdgcn_mfma_f32_16x16x32_bf16(a[kb], bfrag, acc[nt], 0, 0, 0);
    }
  }

  const int col = lane & 15;
  const int rbase = (lane >> 4) * 4;
  #pragma unroll
  for (int nt = 0; nt < 8; ++nt) {
    int n = nt * 16 + col;
    float b = bias[n];
    #pragma unroll
    for (int r = 0; r < 4; ++r) {
      int grow = m_base + rbase + r;
      if (grow < N) Y[(long long)grow * 128 + n] = f2bf(fmaxf(acc[nt][r] + b, 0.f));
    }
  }
}

// ---------------------------------------------------------------------------
// Bin pass: block-local LDS counting sort by bucket, then FULLY COALESCED
// write of the block's records (bucket-grouped) to pktB[block][EPB], plus a
// packed (runOff<<16|runCnt) word per bucket. No global atomics, no scatter.
// ---------------------------------------------------------------------------
__global__ __launch_bounds__(256) void bin_all_kernel(All4 A,
                                                      int2* __restrict__ pktB) {
  int b = blockIdx.x;
  int si = 3;
  if (b < A.s[1].blkBase) si = 0;
  else if (b < A.s[2].blkBase) si = 1;
  else if (b < A.s[3].blkBase) si = 2;
  SetFull d = A.s[si];
  __shared__ int hc[1024];
  __shared__ int hb[1024];
  __shared__ int sh[256];
  __shared__ int2 buf[EPB];
  int tid = threadIdx.x;
  for (int i = tid; i < 1024; i += 256) hc[i] = 0;
  __syncthreads();
  int blkL = b - d.blkBase;
  int e0 = blkL * EPB;
  int de[EPT]; int se[EPT]; float we[EPT];
  #pragma unroll
  for (int it = 0; it < EPT; ++it) {
    int e = e0 + it * 256 + tid;
    bool v = e < d.E;
    de[it] = v ? d.dst[e] : -1;
    se[it] = v ? d.src[e] : 0;
    we[it] = v ? d.w[e] : 0.f;
    if (v) atomicAdd(&hc[de[it] >> d.shift], 1);
  }
  __syncthreads();
  // block exclusive scan of hc[0..1024) -> hb
  int i0 = tid * 4;
  int loc[4];
  int s = 0;
  #pragma unroll
  for (int k = 0; k < 4; ++k) { loc[k] = s; s += hc[i0 + k]; }
  sh[tid] = s;
  __syncthreads();
  #pragma unroll
  for (int off = 1; off < 256; off <<= 1) {
    int t = (tid >= off) ? sh[tid - off] : 0;
    __syncthreads();
    sh[tid] += t;
    __syncthreads();
  }
  int excl = sh[tid] - s;
  #pragma unroll
  for (int k = 0; k < 4; ++k) hb[i0 + k] = excl + loc[k];
  __syncthreads();
  // packed run table (coalesced write); hb then doubles as the LDS cursor
  for (int i = tid; i < d.nb; i += 256)
    d.pkd[blkL * d.nb + i] = (hb[i] << 16) | hc[i];
  __syncthreads();
  int mask = (1 << d.shift) - 1;
  #pragma unroll
  for (int it = 0; it < EPT; ++it) {
    if (de[it] >= 0) {
      int bkt = de[it] >> d.shift;
      int pos = atomicAdd(&hb[bkt], 1);
      buf[pos] = make_int2(((de[it] & mask) << 16) | se[it],
                           __float_as_int(we[it]));
    }
  }
  __syncthreads();
  int4* outp = (int4*)(pktB + (size_t)b * EPB);
  const int4* bp = (const int4*)buf;
  for (int i = tid; i < EPB / 2; i += 256) outp[i] = bp[i];
}

// ---------------------------------------------------------------------------
// Per-bucket sort: gather this bucket's runs from all bin blocks (plain
// reads, deep MLP), LDS row counting sort, coalesced write to pkf slab,
// CSR offsets in per-bucket layout (idx = row + (row>>shift)) + end slot.
// ---------------------------------------------------------------------------
__global__ __launch_bounds__(256) void sort_kernel(All4 A,
                                                   const int2* __restrict__ pktB,
                                                   int2* __restrict__ pkf) {
  int b = blockIdx.x;
  int si = 3;
  if (b < A.s[1].cntBase) si = 0;
  else if (b < A.s[2].cntBase) si = 1;
  else if (b < A.s[3].cntBase) si = 2;
  SetFull d = A.s[si];
  int j = b - d.cntBase;
  int R = 1 << d.shift;
  int rb = j << d.shift;
  int rend = min(rb + R, d.N);
  int nr = rend - rb;
  __shared__ int2 buf[CAP];
  __shared__ int2 buf2[CAP];
  __shared__ int segStart[512];
  __shared__ int pk2[512];
  __shared__ int rowCnt[64];
  __shared__ int rowCur[64];
  __shared__ int sh[256];
  __shared__ int totSh;
  int tid = threadIdx.x;
  // load packed column j for all B blocks of this set; prefix-sum run counts
  int s0 = 2 * tid, s1 = 2 * tid + 1;
  int p0 = (s0 < d.B) ? d.pkd[s0 * d.nb + j] : 0;
  int p1 = (s1 < d.B) ? d.pkd[s1 * d.nb + j] : 0;
  pk2[s0] = p0;
  pk2[s1] = p1;
  int c0 = p0 & 0xffff, c1 = p1 & 0xffff;
  int sum = c0 + c1;
  sh[tid] = sum;
  if (tid < 64) rowCnt[tid] = 0;
  __syncthreads();
  #pragma unroll
  for (int off = 1; off < 256; off <<= 1) {
    int t = (tid >= off) ? sh[tid - off] : 0;
    __syncthreads();
    sh[tid] += t;
    __syncthreads();
  }
  int excl = sh[tid] - sum;
  segStart[s0] = excl;
  segStart[s1] = excl + c0;
  if (tid == 255) totSh = sh[255];
  __syncthreads();
  int cnt = totSh;
  if (cnt > CAP) cnt = CAP;  // statistically unreachable
  // gather runs + row histogram
  for (int s = tid; s < d.B; s += 256) {
    int pk = pk2[s];
    int c = pk & 0xffff;
    int off = pk >> 16;
    int gbase = (d.blkBase + s) * EPB + off;
    int dbase = segStart[s];
    for (int k = 0; k < c; ++k) {
      if (dbase + k < CAP) {
        int2 rec = pktB[gbase + k];
        buf[dbase + k] = rec;
        atomicAdd(&rowCnt[((unsigned)rec.x) >> 16], 1);
      }
    }
  }
  __syncthreads();
  if (tid < 64) {  // wave 0: 64-lane inclusive scan of row counts
    int v = rowCnt[tid];
    int incl = v;
    #pragma unroll
    for (int off = 1; off < 64; off <<= 1) {
      int t = __shfl_up(incl, off);
      if (tid >= off) incl += t;
    }
    int excl2 = incl - v;
    rowCur[tid] = excl2;
    int slabBase = b << CAPSH;
    if (tid < nr) d.offs[rb + j + tid] = slabBase + excl2;
    if (tid == 63) d.offs[rb + j + nr] = slabBase + cnt;
  }
  __syncthreads();
  for (int t = tid; t < cnt; t += 256) {
    int2 rec = buf[t];
    int pos = atomicAdd(&rowCur[((unsigned)rec.x) >> 16], 1);
    buf2[pos] = rec;
  }
  __syncthreads();
  int2* op = pkf + ((size_t)b << CAPSH);
  for (int t = tid; t < cnt; t += 256) op[t] = buf2[t];
}

// ---------------------------------------------------------------------------
// Per-row register pull (bf16 gather), h11+h22 fused.  Full-wave per edge
// (8 gathers in flight).  beg/end scalarized via readfirstlane; full chunks
// carry no per-edge weight mask; single masked tail chunk.
// offs layout: beg = off[row + (row>>6)].
// ---------------------------------------------------------------------------
__global__ __launch_bounds__(256) void pull_h_kernel(
    const int* __restrict__ off1, const int* __restrict__ off2,
    const int2* __restrict__ pk,
    const unsigned* __restrict__ X1, unsigned* __restrict__ Y1, int N1,
    const unsigned* __restrict__ X2, unsigned* __restrict__ Y2, int N2) {
  int row = blockIdx.x * 4 + (threadIdx.x >> 6);
  int lane = threadIdx.x & 63;
  const int* off; const unsigned* X; unsigned* Y;
  if (row < N1) { off = off1; X = X1; Y = Y1; }
  else {
    row -= N1;
    if (row >= N2) return;
    off = off2; X = X2; Y = Y2;
  }
  int idx = row + (row >> 6);
  int beg = __builtin_amdgcn_readfirstlane(off[idx]);
  int end = __builtin_amdgcn_readfirstlane(off[idx + 1]);
  float ax0 = 0.f, ay0 = 0.f, ax1 = 0.f, ay1 = 0.f;
  if (beg < end) {
    int2 p[8], np[8];
    #pragma unroll
    for (int k = 0; k < 8; ++k) p[k] = pk[beg + k];
    int j = beg;
    int fullEnd = beg + ((end - beg) & ~7);
    for (; j < fullEnd; j += 8) {
      #pragma unroll
      for (int k = 0; k < 8; ++k) np[k] = pk[j + 8 + k];
      unsigned v[8];
      #pragma unroll
      for (int k = 0; k < 8; ++k)
        v[k] = X[((p[k].x & 0xffff) << 6) + lane];
      #pragma unroll
      for (int k = 0; k < 8; ++k) {
        float w = __int_as_float(p[k].y);
        if (k & 1) { ax1 += w * bf2f(v[k] & 0xffff); ay1 += w * bf2f(v[k] >> 16); }
        else       { ax0 += w * bf2f(v[k] & 0xffff); ay0 += w * bf2f(v[k] >> 16); }
      }
      #pragma unroll
      for (int k = 0; k < 8; ++k) p[k] = np[k];
    }
    if (j < end) {
      unsigned v[8];
      #pragma unroll
      for (int k = 0; k < 8; ++k)
        v[k] = X[((p[k].x & 0xffff) << 6) + lane];
      #pragma unroll
      for (int k = 0; k < 8; ++k) {
        float w = (j + k < end) ? __int_as_float(p[k].y) : 0.f;
        if (k & 1) { ax1 += w * bf2f(v[k] & 0xffff); ay1 += w * bf2f(v[k] >> 16); }
        else       { ax0 += w * bf2f(v[k] & 0xffff); ay0 += w * bf2f(v[k] >> 16); }
      }
    }
  }
  float ax = ax0 + ax1, ay = ay0 + ay1;
  Y[(row << 6) + lane] = (unsigned)f2bf(ax) | ((unsigned)f2bf(ay) << 16);
}

__device__ __forceinline__ float wave_sum64(float s) {
  #pragma unroll
  for (int off = 32; off; off >>= 1) s += __shfl_xor(s, off);
  return s;
}

// doc2: e01 rows; acc l2_1 & l1_1 (bf16); l2norm; out cols [0,128).
// Full-wave chunk-8 + readfirstlane + tail split. offs: idx = row+(row>>5).
__global__ __launch_bounds__(256) void doc2_kernel(
    const int* __restrict__ offs, const int2* __restrict__ pk,
    const unsigned* __restrict__ Xa, const unsigned* __restrict__ Xb,
    float* __restrict__ out, int N0) {
  int row = blockIdx.x * 4 + (threadIdx.x >> 6);
  int lane = threadIdx.x & 63;
  if (row >= N0) return;
  int idx = row + (row >> 5);
  int beg = __builtin_amdgcn_readfirstlane(offs[idx]);
  int end = __builtin_amdgcn_readfirstlane(offs[idx + 1]);
  float axx = 0.f, axy = 0.f, bxx = 0.f, bxy = 0.f;
  if (beg < end) {
    int2 p[8], np[8];
    #pragma unroll
    for (int k = 0; k < 8; ++k) p[k] = pk[beg + k];
    int j = beg;
    int fullEnd = beg + ((end - beg) & ~7);
    for (; j < fullEnd; j += 8) {
      #pragma unroll
      for (int k = 0; k < 8; ++k) np[k] = pk[j + 8 + k];
      unsigned va[8], vb[8];
      #pragma unroll
      for (int k = 0; k < 8; ++k) {
        int s = ((p[k].x & 0xffff) << 6) + lane;
        va[k] = Xa[s];
        vb[k] = Xb[s];
      }
      #pragma unroll
      for (int k = 0; k < 8; ++k) {
        float w = __int_as_float(p[k].y);
        axx += w * bf2f(va[k] & 0xffff); axy += w * bf2f(va[k] >> 16);
        bxx += w * bf2f(vb[k] & 0xffff); bxy += w * bf2f(vb[k] >> 16);
      }
      #pragma unroll
      for (int k = 0; k < 8; ++k) p[k] = np[k];
    }
    if (j < end) {
      unsigned va[8], vb[8];
      #pragma unroll
      for (int k = 0; k < 8; ++k) {
        int s = ((p[k].x & 0xffff) << 6) + lane;
        va[k] = Xa[s];
        vb[k] = Xb[s];
      }
      #pragma unroll
      for (int k = 0; k < 8; ++k) {
        float w = (j + k < end) ? __int_as_float(p[k].y) : 0.f;
        axx += w * bf2f(va[k] & 0xffff); axy += w * bf2f(va[k] >> 16);
        bxx += w * bf2f(vb[k] & 0xffff); bxy += w * bf2f(vb[k] >> 16);
      }
    }
  }
  const long long DOC = (long long)N0 * 384;
  float sa = wave_sum64(axx * axx + axy * axy);
  float inva = 1.0f / (sqrtf(sa) + 1e-9f);
  ((float2*)(out + (long long)row * 384))[lane] = make_float2(axx * inva, axy * inva);
  float sb = wave_sum64(bxx * bxx + bxy * bxy);
  float invb = 1.0f / (sqrtf(sb) + 1e-9f);
  ((float2*)(out + DOC + (long long)row * 384))[lane] = make_float2(bxx * invb, bxy * invb);
}

// doc3: e02 rows; acc l2_2, l1_2, wem (bf16); l2norm 256-dim.
// Chunk-4 + readfirstlane + tail split.
__global__ __launch_bounds__(256) void doc3_kernel(
    const int* __restrict__ offs, const int2* __restrict__ pk,
    const unsigned* __restrict__ Xa, const unsigned* __restrict__ Xb,
    const unsigned* __restrict__ Xw, float* __restrict__ out, int N0) {
  int row = blockIdx.x * 4 + (threadIdx.x >> 6);
  int lane = threadIdx.x & 63;
  if (row >= N0) return;
  int idx = row + (row >> 5);
  int beg = __builtin_amdgcn_readfirstlane(offs[idx]);
  int end = __builtin_amdgcn_readfirstlane(offs[idx + 1]);
  float axx = 0.f, axy = 0.f, bxx = 0.f, bxy = 0.f, wxx = 0.f, wxy = 0.f;
  if (beg < end) {
    int2 p[4], np[4];
    #pragma unroll
    for (int k = 0; k < 4; ++k) p[k] = pk[beg + k];
    int j = beg;
    int fullEnd = beg + ((end - beg) & ~3);
    for (; j < fullEnd; j += 4) {
      #pragma unroll
      for (int k = 0; k < 4; ++k) np[k] = pk[j + 4 + k];
      unsigned va[4], vb[4], vw[4];
      #pragma unroll
      for (int k = 0; k < 4; ++k) {
        int s = ((p[k].x & 0xffff) << 6) + lane;
        va[k] = Xa[s];
        vb[k] = Xb[s];
        vw[k] = Xw[s];
      }
      #pragma unroll
      for (int k = 0; k < 4; ++k) {
        float w = __int_as_float(p[k].y);
        axx += w * bf2f(va[k] & 0xffff); axy += w * bf2f(va[k] >> 16);
        bxx += w * bf2f(vb[k] & 0xffff); bxy += w * bf2f(vb[k] >> 16);
        wxx += w * bf2f(vw[k] & 0xffff); wxy += w * bf2f(vw[k] >> 16);
      }
      #pragma unroll
      for (int k = 0; k < 4; ++k) p[k] = np[k];
    }
    if (j < end) {
      unsigned va[4], vb[4], vw[4];
      #pragma unroll
      for (int k = 0; k < 4; ++k) {
        int s = ((p[k].x & 0xffff) << 6) + lane;
        va[k] = Xa[s];
        vb[k] = Xb[s];
        vw[k] = Xw[s];
      }
      #pragma unroll
      for (int k = 0; k < 4; ++k) {
        float w = (j + k < end) ? __int_as_float(p[k].y) : 0.f;
        axx += w * bf2f(va[k] & 0xffff); axy += w * bf2f(va[k] >> 16);
        bxx += w * bf2f(vb[k] & 0xffff); bxy += w * bf2f(vb[k] >> 16);
        wxx += w * bf2f(vw[k] & 0xffff); wxy += w * bf2f(vw[k] >> 16);
      }
    }
  }
  const long long DOC = (long long)N0 * 384;
  float swp = wxx * wxx + wxy * wxy;
  float sa = wave_sum64(axx * axx + axy * axy + swp);
  float inva = 1.0f / (sqrtf(sa) + 1e-9f);
  float* o0 = out + (long long)row * 384 + 128;
  ((float2*)o0)[lane] = make_float2(axx * inva, axy * inva);
  ((float2*)(o0 + 128))[lane] = make_float2(wxx * inva, wxy * inva);
  float sb = wave_sum64(bxx * bxx + bxy * bxy + swp);
  float invb = 1.0f / (sqrtf(sb) + 1e-9f);
  float* o1 = out + DOC + (long long)row * 384 + 128;
  ((float2*)o1)[lane] = make_float2(bxx * invb, bxy * invb);
  ((float2*)(o1 + 128))[lane] = make_float2(wxx * invb, wxy * invb);
}

// ---------------------------------------------------------------------------
extern "C" void kernel_launch(void* const* d_in, const int* in_sizes, int n_in,
                              void* d_out, int out_size, void* d_ws,
                              size_t ws_size, hipStream_t stream) {
  const float* x1  = (const float*)d_in[0];
  const float* x2  = (const float*)d_in[1];
  const float* wem = (const float*)d_in[2];
  const float* W1a = (const float*)d_in[3];
  const float* b1a = (const float*)d_in[4];
  const float* W1b = (const float*)d_in[5];
  const float* b1b = (const float*)d_in[6];
  const float* W2a = (const float*)d_in[7];
  const float* b2a = (const float*)d_in[8];
  const float* W2b = (const float*)d_in[9];
  const float* b2b = (const float*)d_in[10];
  const int*   e11s = (const int*)d_in[11];
  const int*   e11d = (const int*)d_in[12];
  const float* e11w = (const float*)d_in[13];
  const int*   e22s = (const int*)d_in[14];
  const int*   e22d = (const int*)d_in[15];
  const float* e22w = (const float*)d_in[16];
  const int*   e01s = (const int*)d_in[17];
  const int*   e01d = (const int*)d_in[18];
  const float* e01w = (const float*)d_in[19];
  const int*   e02s = (const int*)d_in[20];
  const int*   e02d = (const int*)d_in[21];
  const float* e02w = (const float*)d_in[22];

  const int N0 = 10000;
  const int N1 = in_sizes[0] / 256;
  const int N2 = in_sizes[1] / 256;
  const int E11 = in_sizes[11];
  const int E22 = in_sizes[14];
  const int E01 = in_sizes[17];
  const int E02 = in_sizes[20];

  float* out = (float*)d_out;

  // ---- workspace ----
  char* base = (char*)d_ws;
  auto alloc = [&](size_t bytes) -> void* {
    void* r = (void*)base;
    base += (bytes + 255) & ~(size_t)255;
    return r;
  };
  // bf16 feature matrices (packed as unsigned pairs, 64 dwords/row)
  unsigned* l1_1 = (unsigned*)alloc((size_t)N1 * 64 * 4);
  unsigned* l1_2 = (unsigned*)alloc((size_t)N2 * 64 * 4);
  unsigned* l2_1 = (unsigned*)alloc((size_t)N1 * 64 * 4);
  unsigned* l2_2 = (unsigned*)alloc((size_t)N2 * 64 * 4);
  unsigned* h11  = (unsigned*)alloc((size_t)N1 * 64 * 4);
  unsigned* h22  = (unsigned*)alloc((size_t)N2 * 64 * 4);
  unsigned* wemb = (unsigned*)alloc((size_t)N2 * 64 * 4);

  unsigned short* F1a = (unsigned short*)alloc(8 * 8 * 64 * 8 * 2);
  unsigned short* F1b = (unsigned short*)alloc(8 * 4 * 64 * 8 * 2);
  unsigned short* F2a = (unsigned short*)alloc(8 * 8 * 64 * 8 * 2);
  unsigned short* F2b = (unsigned short*)alloc(8 * 4 * 64 * 8 * 2);

  // geometry
  const int nb11 = (N1 + 63) >> 6, nb22 = (N2 + 63) >> 6;
  const int nb01 = (N0 + 31) >> 5, nb02 = (N0 + 31) >> 5;
  const int TOTB = nb11 + nb22 + nb01 + nb02;
  const int B11 = (E11 + EPB - 1) / EPB, B22 = (E22 + EPB - 1) / EPB;
  const int B01 = (E01 + EPB - 1) / EPB, B02 = (E02 + EPB - 1) / EPB;
  const int BT = B11 + B22 + B01 + B02;

  // offs: per-bucket layout, N + nb (+pad)
  int* off11 = (int*)alloc((size_t)(N1 + nb11 + 8) * 4);
  int* off22 = (int*)alloc((size_t)(N2 + nb22 + 8) * 4);
  int* off01 = (int*)alloc((size_t)(N0 + nb01 + 8) * 4);
  int* off02 = (int*)alloc((size_t)(N0 + nb02 + 8) * 4);

  // packed run tables: per set, B rows x nb cols
  int* pkd11 = (int*)alloc((size_t)B11 * nb11 * 4);
  int* pkd22 = (int*)alloc((size_t)B22 * nb22 * 4);
  int* pkd01 = (int*)alloc((size_t)B01 * nb01 * 4);
  int* pkd02 = (int*)alloc((size_t)B02 * nb02 * 4);

  // slab output (sorted records), +16 recs prefetch pad
  int2* pkf = (int2*)alloc(((size_t)TOTB * CAP + 16) * 8);

  // pktB (block-major bin output, dead after sort) ALIASES l2_1/l2_2
  // (written only later): BT*EPB*8 = ~14.1 MB <= l2_1+l2_2 (~20.5 MB).
  int2* pktB = (int2*)l2_1;

  All4 A;
  A.s[0] = {e11s, e11d, e11w, off11, pkd11, E11, N1, 6, nb11, 0, 0, B11};
  A.s[1] = {e22s, e22d, e22w, off22, pkd22, E22, N2, 6, nb22, nb11, B11, B22};
  A.s[2] = {e01s, e01d, e01w, off01, pkd01, E01, N0, 5, nb01, nb11 + nb22,
            B11 + B22, B01};
  A.s[3] = {e02s, e02d, e02w, off02, pkd02, E02, N0, 5, nb02,
            nb11 + nb22 + nb01, B11 + B22 + B01, B02};

  // ---- coalesced bin -> per-bucket gather sort (writes CSR offsets) ----
  bin_all_kernel<<<BT, 256, 0, stream>>>(A, pktB);
  sort_kernel<<<TOTB, 256, 0, stream>>>(A, pktB, pkf);

  // ---- weight + wem conversion, fused layer-1 GEMM ----
  conv_w_kernel<<<48, 256, 0, stream>>>(W1a, W1b, W2a, W2b, F1a, F1b, F2a, F2b);
  conv_bf16_kernel<<<(N2 * 64 + 255) / 256, 256, 0, stream>>>(wem, wemb, N2 * 64);
  gemm1_kernel<256><<<nb11 + nb22, 256, 0, stream>>>(
      x1, F1a, b1a, (unsigned short*)l1_1, N1,
      x2, F2a, b2a, (unsigned short*)l1_2, N2);

  // ---- layer 2: per-row pull then fused GEMM ----
  pull_h_kernel<<<(N1 + N2 + 3) / 4, 256, 0, stream>>>(
      off11, off22, pkf, l1_1, h11, N1, l1_2, h22, N2);
  gemm2_kernel<128><<<nb11 + nb22, 256, 0, stream>>>(
      (const unsigned short*)h11, F1b, b1b, (unsigned short*)l2_1, N1,
      (const unsigned short*)h22, F2b, b2b, (unsigned short*)l2_2, N2);

  // ---- doc aggregation + l2norm + concat ----
  doc2_kernel<<<(N0 + 3) / 4, 256, 0, stream>>>(off01, pkf, l2_1, l1_1, out, N0);
  doc3_kernel<<<(N0 + 3) / 4, 256, 0, stream>>>(off02, pkf, l2_2, l1_2, wemb, out, N0);
}

// Round 10
// 339.905 us; speedup vs baseline: 1.0337x; 1.0337x over previous
//
#include <hip/hip_runtime.h>
#include <math.h>

typedef __attribute__((ext_vector_type(8))) short short8;
typedef __attribute__((ext_vector_type(4))) float float4v;

#define EPB 2048       // edges per block for bin (8/thread)
#define EPT 8
#define CAP 2048       // slab capacity per bucket (mean ~1024, +32 sigma)
#define CAPSH 11

__device__ __forceinline__ unsigned short f2bf(float f) {
  unsigned int u = __float_as_uint(f);
  unsigned int r = (u + 0x7fffu + ((u >> 16) & 1u)) >> 16;  // RNE
  return (unsigned short)r;
}
__device__ __forceinline__ float bf2f(unsigned u16) {
  return __uint_as_float(u16 << 16);
}

struct SetFull {
  const int* src; const int* dst; const float* w;
  int* offs;   // row offsets, per-bucket layout: idx = row + (row>>shift)
  int* pkd;    // packed per-(block,bucket) run table: (off<<16)|cnt
  int E, N, shift, nb, cntBase, blkBase, B;
};
struct All4 { SetFull s[4]; };

// ---------------------------------------------------------------------------
// Weight conversion: W[K][128] fp32 -> frag-major bf16.
// ---------------------------------------------------------------------------
__global__ __launch_bounds__(256) void conv_w_kernel(
    const float* __restrict__ W1a, const float* __restrict__ W1b,
    const float* __restrict__ W2a, const float* __restrict__ W2b,
    unsigned short* __restrict__ F1a, unsigned short* __restrict__ F1b,
    unsigned short* __restrict__ F2a, unsigned short* __restrict__ F2b) {
  int t = blockIdx.x * 256 + threadIdx.x;
  const float* W; unsigned short* F; int KB;
  if (t < 4096) { W = W1a; F = F1a; KB = 8; }
  else if (t < 6144) { W = W1b; F = F1b; KB = 4; t -= 4096; }
  else if (t < 10240) { W = W2a; F = F2a; KB = 8; t -= 6144; }
  else if (t < 12288) { W = W2b; F = F2b; KB = 4; t -= 10240; }
  else return;
  int lane = t & 63;
  int frag = t >> 6;
  int nt = frag / KB;
  int kb = frag - nt * KB;
  int k = kb * 32 + (lane >> 4) * 8;
  int n = nt * 16 + (lane & 15);
  unsigned short v[8];
  #pragma unroll
  for (int j = 0; j < 8; ++j) v[j] = f2bf(W[(long long)(k + j) * 128 + n]);
  unsigned short* o = F + ((long long)frag * 64 + lane) * 8;
  *reinterpret_cast<int4*>(o) = *reinterpret_cast<int4*>(v);
}

// fp32 -> packed bf16 pairs (for word_emb)
__global__ __launch_bounds__(256) void conv_bf16_kernel(
    const float* __restrict__ in, unsigned* __restrict__ out, int npairs) {
  int t = blockIdx.x * 256 + threadIdx.x;
  if (t >= npairs) return;
  float2 v = reinterpret_cast<const float2*>(in)[t];
  out[t] = (unsigned)f2bf(v.x) | ((unsigned)f2bf(v.y) << 16);
}

// ---------------------------------------------------------------------------
// Layer-1 MFMA GEMM, fp32 A (K=256), N1+N2 FUSED: Y bf16 = relu(X@W+b).
// Weights LDS-staged per block; A row preloaded into registers.
// __launch_bounds__(256,2): LDS(64KB) caps at 2 blocks/CU anyway, so grant
// the allocator a 256-VGPR budget — rounds 7-9 failed because the default
// occupancy heuristic capped VGPR at ~85, silently re-serializing the
// 16-deep A preload (VGPR counter stayed 68-88 < the 96 minimum needed).
// ---------------------------------------------------------------------------
template <int K>
__global__ __launch_bounds__(256, 2) void gemm1_kernel(
    const float* __restrict__ X1, const unsigned short* __restrict__ W1,
    const float* __restrict__ bias1, unsigned short* __restrict__ Y1, int N1,
    const float* __restrict__ X2, const unsigned short* __restrict__ W2,
    const float* __restrict__ bias2, unsigned short* __restrict__ Y2, int N2) {
  constexpr int KB = K / 32;
  constexpr int FRAGS = 8 * KB;            // frag count (64 lanes x 16B each)
  __shared__ int4 Flds[FRAGS * 64];        // 64KB for K=256
  const int lane = threadIdx.x & 63;
  const int wave = threadIdx.x >> 6;
  int nb1 = (N1 + 63) >> 6;
  int blk = blockIdx.x;
  const float* X; const unsigned short* Wf; const float* bias;
  unsigned short* Y; int N;
  if (blk < nb1) { X = X1; Wf = W1; bias = bias1; Y = Y1; N = N1; }
  else { blk -= nb1; X = X2; Wf = W2; bias = bias2; Y = Y2; N = N2; }
  const int m_base = blk * 64 + wave * 16;

  int arow = m_base + (lane & 15);
  if (arow >= N) arow = N - 1;
  const float* aptr = X + (long long)arow * K + (lane >> 4) * 8;

  // preload entire A row slice: all 2*KB loads issued back-to-back
  float4 a[2 * KB];
  #pragma unroll
  for (int i = 0; i < 2 * KB; ++i)
    a[i] = *reinterpret_cast<const float4*>(aptr + (i >> 1) * 32 + (i & 1) * 4);
  asm volatile("" ::: "memory");  // pin A loads above staging

  // cooperative weight staging: 16 independent int4 loads, fully unrolled
  {
    const int4* src = (const int4*)Wf;
    #pragma unroll
    for (int it = 0; it < (FRAGS * 64) / 256; ++it)
      Flds[it * 256 + threadIdx.x] = src[it * 256 + threadIdx.x];
  }
  __syncthreads();

  float4v acc[8];
  #pragma unroll
  for (int nt = 0; nt < 8; ++nt) acc[nt] = (float4v)(0.f);

  #pragma unroll
  for (int kb = 0; kb < KB; ++kb) {
    float4 a0 = a[2 * kb];
    float4 a1 = a[2 * kb + 1];
    unsigned short u[8];
    u[0] = f2bf(a0.x); u[1] = f2bf(a0.y); u[2] = f2bf(a0.z); u[3] = f2bf(a0.w);
    u[4] = f2bf(a1.x); u[5] = f2bf(a1.y); u[6] = f2bf(a1.z); u[7] = f2bf(a1.w);
    short8 afrag = *reinterpret_cast<short8*>(u);
    #pragma unroll
    for (int nt = 0; nt < 8; ++nt) {
      int4 braw = Flds[(nt * KB + kb) * 64 + lane];
      short8 bfrag = *reinterpret_cast<short8*>(&braw);
      acc[nt] = __builtin_amdgcn_mfma_f32_16x16x32_bf16(afrag, bfrag, acc[nt], 0, 0, 0);
    }
  }

  const int col = lane & 15;
  const int rbase = (lane >> 4) * 4;
  #pragma unroll
  for (int nt = 0; nt < 8; ++nt) {
    int n = nt * 16 + col;
    float b = bias[n];
    #pragma unroll
    for (int r = 0; r < 4; ++r) {
      int grow = m_base + rbase + r;
      if (grow < N) Y[(long long)grow * 128 + n] = f2bf(fmaxf(acc[nt][r] + b, 0.f));
    }
  }
}

// ---------------------------------------------------------------------------
// Layer-2 MFMA GEMM, bf16 A (K=128), h11+h22 FUSED. Weights LDS-staged (32KB).
// __launch_bounds__(256,4): 128-VGPR cap, comfortably fits a[4]+acc+staging.
// ---------------------------------------------------------------------------
template <int K>
__global__ __launch_bounds__(256, 4) void gemm2_kernel(
    const unsigned short* __restrict__ X1, const unsigned short* __restrict__ W1,
    const float* __restrict__ bias1, unsigned short* __restrict__ Y1, int N1,
    const unsigned short* __restrict__ X2, const unsigned short* __restrict__ W2,
    const float* __restrict__ bias2, unsigned short* __restrict__ Y2, int N2) {
  constexpr int KB = K / 32;
  constexpr int FRAGS = 8 * KB;
  __shared__ int4 Flds[FRAGS * 64];        // 32KB for K=128
  const int lane = threadIdx.x & 63;
  const int wave = threadIdx.x >> 6;
  int nb1 = (N1 + 63) >> 6;
  int blk = blockIdx.x;
  const unsigned short* X; const unsigned short* Wf; const float* bias;
  unsigned short* Y; int N;
  if (blk < nb1) { X = X1; Wf = W1; bias = bias1; Y = Y1; N = N1; }
  else { blk -= nb1; X = X2; Wf = W2; bias = bias2; Y = Y2; N = N2; }
  const int m_base = blk * 64 + wave * 16;

  int arow = m_base + (lane & 15);
  if (arow >= N) arow = N - 1;
  const unsigned short* aptr = X + (long long)arow * K + (lane >> 4) * 8;

  short8 a[KB];
  #pragma unroll
  for (int kb = 0; kb < KB; ++kb)
    a[kb] = *reinterpret_cast<const short8*>(aptr + kb * 32);
  asm volatile("" ::: "memory");  // pin A loads above staging

  {
    const int4* src = (const int4*)Wf;
    #pragma unroll
    for (int it = 0; it < (FRAGS * 64) / 256; ++it)
      Flds[it * 256 + threadIdx.x] = src[it * 256 + threadIdx.x];
  }
  __syncthreads();

  float4v acc[8];
  #pragma unroll
  for (int nt = 0; nt < 8; ++nt) acc[nt] = (float4v)(0.f);

  #pragma unroll
  for (int kb = 0; kb < KB; ++kb) {
    #pragma unroll
    for (int nt = 0; nt < 8; ++nt) {
      int4 braw = Flds[(nt * KB + kb) * 64 + lane];
      short8 bfrag = *reinterpret_cast<short8*>(&braw);
      acc[nt] = __builtin_amdgcn_mfma_f32_16x16x32_bf16(a[kb], bfrag, acc[nt], 0, 0, 0);
    }
  }

  const int col = lane & 15;
  const int rbase = (lane >> 4) * 4;
  #pragma unroll
  for (int nt = 0; nt < 8; ++nt) {
    int n = nt * 16 + col;
    float b = bias[n];
    #pragma unroll
    for (int r = 0; r < 4; ++r) {
      int grow = m_base + rbase + r;
      if (grow < N) Y[(long long)grow * 128 + n] = f2bf(fmaxf(acc[nt][r] + b, 0.f));
    }
  }
}

// ---------------------------------------------------------------------------
// Bin pass: block-local LDS counting sort by bucket, then FULLY COALESCED
// write of the block's records (bucket-grouped) to pktB[block][EPB], plus a
// packed (runOff<<16|runCnt) word per bucket. No global atomics, no scatter.
// ---------------------------------------------------------------------------
__global__ __launch_bounds__(256) void bin_all_kernel(All4 A,
                                                      int2* __restrict__ pktB) {
  int b = blockIdx.x;
  int si = 3;
  if (b < A.s[1].blkBase) si = 0;
  else if (b < A.s[2].blkBase) si = 1;
  else if (b < A.s[3].blkBase) si = 2;
  SetFull d = A.s[si];
  __shared__ int hc[1024];
  __shared__ int hb[1024];
  __shared__ int sh[256];
  __shared__ int2 buf[EPB];
  int tid = threadIdx.x;
  for (int i = tid; i < 1024; i += 256) hc[i] = 0;
  __syncthreads();
  int blkL = b - d.blkBase;
  int e0 = blkL * EPB;
  int de[EPT]; int se[EPT]; float we[EPT];
  #pragma unroll
  for (int it = 0; it < EPT; ++it) {
    int e = e0 + it * 256 + tid;
    bool v = e < d.E;
    de[it] = v ? d.dst[e] : -1;
    se[it] = v ? d.src[e] : 0;
    we[it] = v ? d.w[e] : 0.f;
    if (v) atomicAdd(&hc[de[it] >> d.shift], 1);
  }
  __syncthreads();
  // block exclusive scan of hc[0..1024) -> hb
  int i0 = tid * 4;
  int loc[4];
  int s = 0;
  #pragma unroll
  for (int k = 0; k < 4; ++k) { loc[k] = s; s += hc[i0 + k]; }
  sh[tid] = s;
  __syncthreads();
  #pragma unroll
  for (int off = 1; off < 256; off <<= 1) {
    int t = (tid >= off) ? sh[tid - off] : 0;
    __syncthreads();
    sh[tid] += t;
    __syncthreads();
  }
  int excl = sh[tid] - s;
  #pragma unroll
  for (int k = 0; k < 4; ++k) hb[i0 + k] = excl + loc[k];
  __syncthreads();
  // packed run table (coalesced write); hb then doubles as the LDS cursor
  for (int i = tid; i < d.nb; i += 256)
    d.pkd[blkL * d.nb + i] = (hb[i] << 16) | hc[i];
  __syncthreads();
  int mask = (1 << d.shift) - 1;
  #pragma unroll
  for (int it = 0; it < EPT; ++it) {
    if (de[it] >= 0) {
      int bkt = de[it] >> d.shift;
      int pos = atomicAdd(&hb[bkt], 1);
      buf[pos] = make_int2(((de[it] & mask) << 16) | se[it],
                           __float_as_int(we[it]));
    }
  }
  __syncthreads();
  int4* outp = (int4*)(pktB + (size_t)b * EPB);
  const int4* bp = (const int4*)buf;
  for (int i = tid; i < EPB / 2; i += 256) outp[i] = bp[i];
}

// ---------------------------------------------------------------------------
// Per-bucket sort: gather this bucket's runs from all bin blocks (plain
// reads, deep MLP), LDS row counting sort, coalesced write to pkf slab,
// CSR offsets in per-bucket layout (idx = row + (row>>shift)) + end slot.
// ---------------------------------------------------------------------------
__global__ __launch_bounds__(256) void sort_kernel(All4 A,
                                                   const int2* __restrict__ pktB,
                                                   int2* __restrict__ pkf) {
  int b = blockIdx.x;
  int si = 3;
  if (b < A.s[1].cntBase) si = 0;
  else if (b < A.s[2].cntBase) si = 1;
  else if (b < A.s[3].cntBase) si = 2;
  SetFull d = A.s[si];
  int j = b - d.cntBase;
  int R = 1 << d.shift;
  int rb = j << d.shift;
  int rend = min(rb + R, d.N);
  int nr = rend - rb;
  __shared__ int2 buf[CAP];
  __shared__ int2 buf2[CAP];
  __shared__ int segStart[512];
  __shared__ int pk2[512];
  __shared__ int rowCnt[64];
  __shared__ int rowCur[64];
  __shared__ int sh[256];
  __shared__ int totSh;
  int tid = threadIdx.x;
  // load packed column j for all B blocks of this set; prefix-sum run counts
  int s0 = 2 * tid, s1 = 2 * tid + 1;
  int p0 = (s0 < d.B) ? d.pkd[s0 * d.nb + j] : 0;
  int p1 = (s1 < d.B) ? d.pkd[s1 * d.nb + j] : 0;
  pk2[s0] = p0;
  pk2[s1] = p1;
  int c0 = p0 & 0xffff, c1 = p1 & 0xffff;
  int sum = c0 + c1;
  sh[tid] = sum;
  if (tid < 64) rowCnt[tid] = 0;
  __syncthreads();
  #pragma unroll
  for (int off = 1; off < 256; off <<= 1) {
    int t = (tid >= off) ? sh[tid - off] : 0;
    __syncthreads();
    sh[tid] += t;
    __syncthreads();
  }
  int excl = sh[tid] - sum;
  segStart[s0] = excl;
  segStart[s1] = excl + c0;
  if (tid == 255) totSh = sh[255];
  __syncthreads();
  int cnt = totSh;
  if (cnt > CAP) cnt = CAP;  // statistically unreachable
  // gather runs + row histogram
  for (int s = tid; s < d.B; s += 256) {
    int pk = pk2[s];
    int c = pk & 0xffff;
    int off = pk >> 16;
    int gbase = (d.blkBase + s) * EPB + off;
    int dbase = segStart[s];
    for (int k = 0; k < c; ++k) {
      if (dbase + k < CAP) {
        int2 rec = pktB[gbase + k];
        buf[dbase + k] = rec;
        atomicAdd(&rowCnt[((unsigned)rec.x) >> 16], 1);
      }
    }
  }
  __syncthreads();
  if (tid < 64) {  // wave 0: 64-lane inclusive scan of row counts
    int v = rowCnt[tid];
    int incl = v;
    #pragma unroll
    for (int off = 1; off < 64; off <<= 1) {
      int t = __shfl_up(incl, off);
      if (tid >= off) incl += t;
    }
    int excl2 = incl - v;
    rowCur[tid] = excl2;
    int slabBase = b << CAPSH;
    if (tid < nr) d.offs[rb + j + tid] = slabBase + excl2;
    if (tid == 63) d.offs[rb + j + nr] = slabBase + cnt;
  }
  __syncthreads();
  for (int t = tid; t < cnt; t += 256) {
    int2 rec = buf[t];
    int pos = atomicAdd(&rowCur[((unsigned)rec.x) >> 16], 1);
    buf2[pos] = rec;
  }
  __syncthreads();
  int2* op = pkf + ((size_t)b << CAPSH);
  for (int t = tid; t < cnt; t += 256) op[t] = buf2[t];
}

// ---------------------------------------------------------------------------
// Per-row register pull (bf16 gather), h11+h22 fused.  Full-wave per edge
// (8 gathers in flight).  beg/end scalarized via readfirstlane; full chunks
// carry no per-edge weight mask; single masked tail chunk.
// offs layout: beg = off[row + (row>>6)].
// ---------------------------------------------------------------------------
__global__ __launch_bounds__(256) void pull_h_kernel(
    const int* __restrict__ off1, const int* __restrict__ off2,
    const int2* __restrict__ pk,
    const unsigned* __restrict__ X1, unsigned* __restrict__ Y1, int N1,
    const unsigned* __restrict__ X2, unsigned* __restrict__ Y2, int N2) {
  int row = blockIdx.x * 4 + (threadIdx.x >> 6);
  int lane = threadIdx.x & 63;
  const int* off; const unsigned* X; unsigned* Y;
  if (row < N1) { off = off1; X = X1; Y = Y1; }
  else {
    row -= N1;
    if (row >= N2) return;
    off = off2; X = X2; Y = Y2;
  }
  int idx = row + (row >> 6);
  int beg = __builtin_amdgcn_readfirstlane(off[idx]);
  int end = __builtin_amdgcn_readfirstlane(off[idx + 1]);
  float ax0 = 0.f, ay0 = 0.f, ax1 = 0.f, ay1 = 0.f;
  if (beg < end) {
    int2 p[8], np[8];
    #pragma unroll
    for (int k = 0; k < 8; ++k) p[k] = pk[beg + k];
    int j = beg;
    int fullEnd = beg + ((end - beg) & ~7);
    for (; j < fullEnd; j += 8) {
      #pragma unroll
      for (int k = 0; k < 8; ++k) np[k] = pk[j + 8 + k];
      unsigned v[8];
      #pragma unroll
      for (int k = 0; k < 8; ++k)
        v[k] = X[((p[k].x & 0xffff) << 6) + lane];
      #pragma unroll
      for (int k = 0; k < 8; ++k) {
        float w = __int_as_float(p[k].y);
        if (k & 1) { ax1 += w * bf2f(v[k] & 0xffff); ay1 += w * bf2f(v[k] >> 16); }
        else       { ax0 += w * bf2f(v[k] & 0xffff); ay0 += w * bf2f(v[k] >> 16); }
      }
      #pragma unroll
      for (int k = 0; k < 8; ++k) p[k] = np[k];
    }
    if (j < end) {
      unsigned v[8];
      #pragma unroll
      for (int k = 0; k < 8; ++k)
        v[k] = X[((p[k].x & 0xffff) << 6) + lane];
      #pragma unroll
      for (int k = 0; k < 8; ++k) {
        float w = (j + k < end) ? __int_as_float(p[k].y) : 0.f;
        if (k & 1) { ax1 += w * bf2f(v[k] & 0xffff); ay1 += w * bf2f(v[k] >> 16); }
        else       { ax0 += w * bf2f(v[k] & 0xffff); ay0 += w * bf2f(v[k] >> 16); }
      }
    }
  }
  float ax = ax0 + ax1, ay = ay0 + ay1;
  Y[(row << 6) + lane] = (unsigned)f2bf(ax) | ((unsigned)f2bf(ay) << 16);
}

__device__ __forceinline__ float wave_sum64(float s) {
  #pragma unroll
  for (int off = 32; off; off >>= 1) s += __shfl_xor(s, off);
  return s;
}

// doc2: e01 rows; acc l2_1 & l1_1 (bf16); l2norm; out cols [0,128).
// Full-wave chunk-8 + readfirstlane + tail split. offs: idx = row+(row>>5).
__global__ __launch_bounds__(256) void doc2_kernel(
    const int* __restrict__ offs, const int2* __restrict__ pk,
    const unsigned* __restrict__ Xa, const unsigned* __restrict__ Xb,
    float* __restrict__ out, int N0) {
  int row = blockIdx.x * 4 + (threadIdx.x >> 6);
  int lane = threadIdx.x & 63;
  if (row >= N0) return;
  int idx = row + (row >> 5);
  int beg = __builtin_amdgcn_readfirstlane(offs[idx]);
  int end = __builtin_amdgcn_readfirstlane(offs[idx + 1]);
  float axx = 0.f, axy = 0.f, bxx = 0.f, bxy = 0.f;
  if (beg < end) {
    int2 p[8], np[8];
    #pragma unroll
    for (int k = 0; k < 8; ++k) p[k] = pk[beg + k];
    int j = beg;
    int fullEnd = beg + ((end - beg) & ~7);
    for (; j < fullEnd; j += 8) {
      #pragma unroll
      for (int k = 0; k < 8; ++k) np[k] = pk[j + 8 + k];
      unsigned va[8], vb[8];
      #pragma unroll
      for (int k = 0; k < 8; ++k) {
        int s = ((p[k].x & 0xffff) << 6) + lane;
        va[k] = Xa[s];
        vb[k] = Xb[s];
      }
      #pragma unroll
      for (int k = 0; k < 8; ++k) {
        float w = __int_as_float(p[k].y);
        axx += w * bf2f(va[k] & 0xffff); axy += w * bf2f(va[k] >> 16);
        bxx += w * bf2f(vb[k] & 0xffff); bxy += w * bf2f(vb[k] >> 16);
      }
      #pragma unroll
      for (int k = 0; k < 8; ++k) p[k] = np[k];
    }
    if (j < end) {
      unsigned va[8], vb[8];
      #pragma unroll
      for (int k = 0; k < 8; ++k) {
        int s = ((p[k].x & 0xffff) << 6) + lane;
        va[k] = Xa[s];
        vb[k] = Xb[s];
      }
      #pragma unroll
      for (int k = 0; k < 8; ++k) {
        float w = (j + k < end) ? __int_as_float(p[k].y) : 0.f;
        axx += w * bf2f(va[k] & 0xffff); axy += w * bf2f(va[k] >> 16);
        bxx += w * bf2f(vb[k] & 0xffff); bxy += w * bf2f(vb[k] >> 16);
      }
    }
  }
  const long long DOC = (long long)N0 * 384;
  float sa = wave_sum64(axx * axx + axy * axy);
  float inva = 1.0f / (sqrtf(sa) + 1e-9f);
  ((float2*)(out + (long long)row * 384))[lane] = make_float2(axx * inva, axy * inva);
  float sb = wave_sum64(bxx * bxx + bxy * bxy);
  float invb = 1.0f / (sqrtf(sb) + 1e-9f);
  ((float2*)(out + DOC + (long long)row * 384))[lane] = make_float2(bxx * invb, bxy * invb);
}

// doc3: e02 rows; acc l2_2, l1_2, wem (bf16); l2norm 256-dim.
// Chunk-4 + readfirstlane + tail split.
__global__ __launch_bounds__(256) void doc3_kernel(
    const int* __restrict__ offs, const int2* __restrict__ pk,
    const unsigned* __restrict__ Xa, const unsigned* __restrict__ Xb,
    const unsigned* __restrict__ Xw, float* __restrict__ out, int N0) {
  int row = blockIdx.x * 4 + (threadIdx.x >> 6);
  int lane = threadIdx.x & 63;
  if (row >= N0) return;
  int idx = row + (row >> 5);
  int beg = __builtin_amdgcn_readfirstlane(offs[idx]);
  int end = __builtin_amdgcn_readfirstlane(offs[idx + 1]);
  float axx = 0.f, axy = 0.f, bxx = 0.f, bxy = 0.f, wxx = 0.f, wxy = 0.f;
  if (beg < end) {
    int2 p[4], np[4];
    #pragma unroll
    for (int k = 0; k < 4; ++k) p[k] = pk[beg + k];
    int j = beg;
    int fullEnd = beg + ((end - beg) & ~3);
    for (; j < fullEnd; j += 4) {
      #pragma unroll
      for (int k = 0; k < 4; ++k) np[k] = pk[j + 4 + k];
      unsigned va[4], vb[4], vw[4];
      #pragma unroll
      for (int k = 0; k < 4; ++k) {
        int s = ((p[k].x & 0xffff) << 6) + lane;
        va[k] = Xa[s];
        vb[k] = Xb[s];
        vw[k] = Xw[s];
      }
      #pragma unroll
      for (int k = 0; k < 4; ++k) {
        float w = __int_as_float(p[k].y);
        axx += w * bf2f(va[k] & 0xffff); axy += w * bf2f(va[k] >> 16);
        bxx += w * bf2f(vb[k] & 0xffff); bxy += w * bf2f(vb[k] >> 16);
        wxx += w * bf2f(vw[k] & 0xffff); wxy += w * bf2f(vw[k] >> 16);
      }
      #pragma unroll
      for (int k = 0; k < 4; ++k) p[k] = np[k];
    }
    if (j < end) {
      unsigned va[4], vb[4], vw[4];
      #pragma unroll
      for (int k = 0; k < 4; ++k) {
        int s = ((p[k].x & 0xffff) << 6) + lane;
        va[k] = Xa[s];
        vb[k] = Xb[s];
        vw[k] = Xw[s];
      }
      #pragma unroll
      for (int k = 0; k < 4; ++k) {
        float w = (j + k < end) ? __int_as_float(p[k].y) : 0.f;
        axx += w * bf2f(va[k] & 0xffff); axy += w * bf2f(va[k] >> 16);
        bxx += w * bf2f(vb[k] & 0xffff); bxy += w * bf2f(vb[k] >> 16);
        wxx += w * bf2f(vw[k] & 0xffff); wxy += w * bf2f(vw[k] >> 16);
      }
    }
  }
  const long long DOC = (long long)N0 * 384;
  float swp = wxx * wxx + wxy * wxy;
  float sa = wave_sum64(axx * axx + axy * axy + swp);
  float inva = 1.0f / (sqrtf(sa) + 1e-9f);
  float* o0 = out + (long long)row * 384 + 128;
  ((float2*)o0)[lane] = make_float2(axx * inva, axy * inva);
  ((float2*)(o0 + 128))[lane] = make_float2(wxx * inva, wxy * inva);
  float sb = wave_sum64(bxx * bxx + bxy * bxy + swp);
  float invb = 1.0f / (sqrtf(sb) + 1e-9f);
  float* o1 = out + DOC + (long long)row * 384 + 128;
  ((float2*)o1)[lane] = make_float2(bxx * invb, bxy * invb);
  ((float2*)(o1 + 128))[lane] = make_float2(wxx * invb, wxy * invb);
}

// ---------------------------------------------------------------------------
extern "C" void kernel_launch(void* const* d_in, const int* in_sizes, int n_in,
                              void* d_out, int out_size, void* d_ws,
                              size_t ws_size, hipStream_t stream) {
  const float* x1  = (const float*)d_in[0];
  const float* x2  = (const float*)d_in[1];
  const float* wem = (const float*)d_in[2];
  const float* W1a = (const float*)d_in[3];
  const float* b1a = (const float*)d_in[4];
  const float* W1b = (const float*)d_in[5];
  const float* b1b = (const float*)d_in[6];
  const float* W2a = (const float*)d_in[7];
  const float* b2a = (const float*)d_in[8];
  const float* W2b = (const float*)d_in[9];
  const float* b2b = (const float*)d_in[10];
  const int*   e11s = (const int*)d_in[11];
  const int*   e11d = (const int*)d_in[12];
  const float* e11w = (const float*)d_in[13];
  const int*   e22s = (const int*)d_in[14];
  const int*   e22d = (const int*)d_in[15];
  const float* e22w = (const float*)d_in[16];
  const int*   e01s = (const int*)d_in[17];
  const int*   e01d = (const int*)d_in[18];
  const float* e01w = (const float*)d_in[19];
  const int*   e02s = (const int*)d_in[20];
  const int*   e02d = (const int*)d_in[21];
  const float* e02w = (const float*)d_in[22];

  const int N0 = 10000;
  const int N1 = in_sizes[0] / 256;
  const int N2 = in_sizes[1] / 256;
  const int E11 = in_sizes[11];
  const int E22 = in_sizes[14];
  const int E01 = in_sizes[17];
  const int E02 = in_sizes[20];

  float* out = (float*)d_out;

  // ---- workspace ----
  char* base = (char*)d_ws;
  auto alloc = [&](size_t bytes) -> void* {
    void* r = (void*)base;
    base += (bytes + 255) & ~(size_t)255;
    return r;
  };
  // bf16 feature matrices (packed as unsigned pairs, 64 dwords/row)
  unsigned* l1_1 = (unsigned*)alloc((size_t)N1 * 64 * 4);
  unsigned* l1_2 = (unsigned*)alloc((size_t)N2 * 64 * 4);
  unsigned* l2_1 = (unsigned*)alloc((size_t)N1 * 64 * 4);
  unsigned* l2_2 = (unsigned*)alloc((size_t)N2 * 64 * 4);
  unsigned* h11  = (unsigned*)alloc((size_t)N1 * 64 * 4);
  unsigned* h22  = (unsigned*)alloc((size_t)N2 * 64 * 4);
  unsigned* wemb = (unsigned*)alloc((size_t)N2 * 64 * 4);

  unsigned short* F1a = (unsigned short*)alloc(8 * 8 * 64 * 8 * 2);
  unsigned short* F1b = (unsigned short*)alloc(8 * 4 * 64 * 8 * 2);
  unsigned short* F2a = (unsigned short*)alloc(8 * 8 * 64 * 8 * 2);
  unsigned short* F2b = (unsigned short*)alloc(8 * 4 * 64 * 8 * 2);

  // geometry
  const int nb11 = (N1 + 63) >> 6, nb22 = (N2 + 63) >> 6;
  const int nb01 = (N0 + 31) >> 5, nb02 = (N0 + 31) >> 5;
  const int TOTB = nb11 + nb22 + nb01 + nb02;
  const int B11 = (E11 + EPB - 1) / EPB, B22 = (E22 + EPB - 1) / EPB;
  const int B01 = (E01 + EPB - 1) / EPB, B02 = (E02 + EPB - 1) / EPB;
  const int BT = B11 + B22 + B01 + B02;

  // offs: per-bucket layout, N + nb (+pad)
  int* off11 = (int*)alloc((size_t)(N1 + nb11 + 8) * 4);
  int* off22 = (int*)alloc((size_t)(N2 + nb22 + 8) * 4);
  int* off01 = (int*)alloc((size_t)(N0 + nb01 + 8) * 4);
  int* off02 = (int*)alloc((size_t)(N0 + nb02 + 8) * 4);

  // packed run tables: per set, B rows x nb cols
  int* pkd11 = (int*)alloc((size_t)B11 * nb11 * 4);
  int* pkd22 = (int*)alloc((size_t)B22 * nb22 * 4);
  int* pkd01 = (int*)alloc((size_t)B01 * nb01 * 4);
  int* pkd02 = (int*)alloc((size_t)B02 * nb02 * 4);

  // slab output (sorted records), +16 recs prefetch pad
  int2* pkf = (int2*)alloc(((size_t)TOTB * CAP + 16) * 8);

  // pktB (block-major bin output, dead after sort) ALIASES l2_1/l2_2
  // (written only later): BT*EPB*8 = ~14.1 MB <= l2_1+l2_2 (~20.5 MB).
  int2* pktB = (int2*)l2_1;

  All4 A;
  A.s[0] = {e11s, e11d, e11w, off11, pkd11, E11, N1, 6, nb11, 0, 0, B11};
  A.s[1] = {e22s, e22d, e22w, off22, pkd22, E22, N2, 6, nb22, nb11, B11, B22};
  A.s[2] = {e01s, e01d, e01w, off01, pkd01, E01, N0, 5, nb01, nb11 + nb22,
            B11 + B22, B01};
  A.s[3] = {e02s, e02d, e02w, off02, pkd02, E02, N0, 5, nb02,
            nb11 + nb22 + nb01, B11 + B22 + B01, B02};

  // ---- coalesced bin -> per-bucket gather sort (writes CSR offsets) ----
  bin_all_kernel<<<BT, 256, 0, stream>>>(A, pktB);
  sort_kernel<<<TOTB, 256, 0, stream>>>(A, pktB, pkf);

  // ---- weight + wem conversion, fused layer-1 GEMM ----
  conv_w_kernel<<<48, 256, 0, stream>>>(W1a, W1b, W2a, W2b, F1a, F1b, F2a, F2b);
  conv_bf16_kernel<<<(N2 * 64 + 255) / 256, 256, 0, stream>>>(wem, wemb, N2 * 64);
  gemm1_kernel<256><<<nb11 + nb22, 256, 0, stream>>>(
      x1, F1a, b1a, (unsigned short*)l1_1, N1,
      x2, F2a, b2a, (unsigned short*)l1_2, N2);

  // ---- layer 2: per-row pull then fused GEMM ----
  pull_h_kernel<<<(N1 + N2 + 3) / 4, 256, 0, stream>>>(
      off11, off22, pkf, l1_1, h11, N1, l1_2, h22, N2);
  gemm2_kernel<128><<<nb11 + nb22, 256, 0, stream>>>(
      (const unsigned short*)h11, F1b, b1b, (unsigned short*)l2_1, N1,
      (const unsigned short*)h22, F2b, b2b, (unsigned short*)l2_2, N2);

  // ---- doc aggregation + l2norm + concat ----
  doc2_kernel<<<(N0 + 3) / 4, 256, 0, stream>>>(off01, pkf, l2_1, l1_1, out, N0);
  doc3_kernel<<<(N0 + 3) / 4, 256, 0, stream>>>(off02, pkf, l2_2, l1_2, wemb, out, N0);
}